// Round 4
// baseline (6245.937 us; speedup 1.0000x reference)
//
#include <hip/hip_runtime.h>
#include <hip/hip_bf16.h>

// 2-layer GRU decoder, persistent MFMA kernel. B=128, T=1024, H=200.
// R4: 16 batch-groups (8 batch) x 16 hidden-slices = 256 blocks, 256 thr.
// - Sync: NO barriers/flags. Each h dword carries a freshness tag in bit 16
//   (lo-bf16 mantissa LSB, error <= 2^-16|h|). Consumers poll+retry their own
//   staged loads. Buffers pre-filled with 0x00010000 (h=0, tag=1) by init kernel.
// - Weights as bf16 hi/lo MFMA A-fragments in registers (112 VGPR/wave).
//   bf16x3 MFMA (Ah*Bh + Ah*Bl + Al*Bh) for fp32-grade precision.
// - K extended 200->208: x (teacher-forced input + emotion) packed into B rows
//   200..207; Wih0 folded into r,z rows of Whh0. n-gate keeps a tiny fp32 dot.
// - NB=8: B-fragment lanes n and n+8 share LDS addresses (broadcast) -> 4-way
//   max conflicts on ds_read_b128 (row stride 228 % 8 == 4).

#define TT   1024
#define HH   200
#define NBB  8
#define HS   13
#define KP   228     // hB row stride in dwords
#define HBUF 25600   // one h buffer (128*200 dwords)

typedef __attribute__((ext_vector_type(8))) short short8;
typedef __attribute__((ext_vector_type(4))) float f32x4;

__device__ __forceinline__ float sigm(float v) { return 1.0f / (1.0f + __expf(-v)); }
__device__ __forceinline__ float tanh_fast(float v) {
  float e = __expf(-2.0f * v);
  return (1.0f - e) / (1.0f + e);
}
__device__ __forceinline__ uint llc_load_u32(const uint* p) {
  return __hip_atomic_load(p, __ATOMIC_RELAXED, __HIP_MEMORY_SCOPE_SYSTEM);
}
__device__ __forceinline__ void llc_store_u32(uint* p, uint v) {
  __hip_atomic_store(p, v, __ATOMIC_RELAXED, __HIP_MEMORY_SCOPE_SYSTEM);
}
__device__ __forceinline__ float bfu2f(ushort u) { return __uint_as_float(((uint)u) << 16); }
__device__ __forceinline__ ushort f2bfu(float f) {
  __hip_bfloat16 b = __float2bfloat16(f);
  return *(ushort*)&b;
}
__device__ __forceinline__ uint packf_tag(float h, uint tag) {
  ushort hi = f2bfu(h);
  ushort lo = f2bfu(h - bfu2f(hi));
  return (uint)hi | ((((uint)lo & 0xFFFEu) | tag) << 16);
}
__device__ __forceinline__ uint packf_nt(float h) {
  ushort hi = f2bfu(h);
  ushort lo = f2bfu(h - bfu2f(hi));
  return (uint)hi | (((uint)lo) << 16);
}
__device__ __forceinline__ float upk(uint u) {
  return __uint_as_float(u << 16) + __uint_as_float(u & 0xFFFF0000u);
}

__global__ void init_state(uint* p) {
  int i = blockIdx.x * 256 + threadIdx.x;
  if (i < 4 * HBUF) llc_store_u32(p + i, 0x00010000u);  // h=0, tag=1
}

__global__ __launch_bounds__(256, 2) void gru2_tag(
    const float* __restrict__ x,
    const float* __restrict__ Wih0, const float* __restrict__ Whh0,
    const float* __restrict__ bih0, const float* __restrict__ bhh0,
    const float* __restrict__ Wih1, const float* __restrict__ Whh1,
    const float* __restrict__ bih1, const float* __restrict__ bhh1,
    const float* __restrict__ Wfc,  const float* __restrict__ bfc,
    float* __restrict__ out,
    uint* __restrict__ h0g, uint* __restrict__ h1g)
{
  __shared__ __align__(16) uint hB[2][NBB][KP];   // packed (hi | lo<<16) bf16 pairs
  __shared__ float D[128][9];                     // GEMM results, p-space rows
  __shared__ float xc[2][NBB][8];
  __shared__ float Wi0n[HS][8];
  __shared__ float bs0rz[2 * HS], b0ni[HS], b0nh[HS];
  __shared__ float bs1rz[2 * HS], b1ni[HS], b1nh[HS], bfcs[4];

  const int tid  = threadIdx.x;
  const int wave = tid >> 6;
  const int lane = tid & 63;
  const int m15  = lane & 15;
  const int q    = lane >> 4;

  const int g  = blockIdx.x & 15;    // batch-group
  const int s  = blockIdx.x >> 4;    // hidden-slice
  const int b0 = g * NBB;
  const int j0 = s * HS;
  const int hs = (HH - j0 < HS) ? (HH - j0) : HS;  // 13, or 5 for s==15
  const int th  = 3 * hs;
  const int h0r = 6 * hs;                           // rows dotted with h0
  const int T0  = (h0r + 15) >> 4;                  // 5 (hs13) / 2 (hs5)
  const int NT  = T0 + ((th + 15) >> 4);            // 8 / 3
  const bool isOut = (s == 15);

  // ---- one-time: A-fragments (hi/lo bf16) into registers; K in [0,208) ----
  // p-space row r: [0,h0r) -> st0 rows {Whh0 r,z,n | Wih1 r,z,n};
  // [T0*16, T0*16+th) -> st1 rows {Whh1 r,z,n}; rest dead (zero).
  // Whh0 r,z rows carry Wih0 in k=200..207. FC tile (isOut, T==NT): Wfc.
  short8 Ah[2][7], Al[2][7];
  #pragma unroll
  for (int tt = 0; tt < 2; ++tt) {
    const int T = 2 * wave + tt;
    const bool isFC = isOut && (T == NT);
    const bool val  = (T < NT) || isFC;
    #pragma unroll
    for (int kt = 0; kt < 7; ++kt) {
      short8 vh = {0,0,0,0,0,0,0,0}, vl = {0,0,0,0,0,0,0,0};
      if (val) {
        #pragma unroll
        for (int j = 0; j < 8; ++j) {
          const int k = kt * 32 + q * 8 + j;
          float w = 0.0f;
          const int p = T * 16 + m15;
          if (isFC) {
            if (m15 < 4 && k < HH) w = Wfc[m15 * HH + k];
          } else {
            int r = -1;
            if (p < h0r) r = p;
            else { int pp = p - T0 * 16; if (pp >= 0 && pp < th) r = h0r + pp; }
            if (r >= 0) {
              const int m = r / th, rr = r - m * th;
              const int q3 = rr / hs, jj = rr - q3 * hs;
              const int grow = q3 * HH + j0 + jj;
              if (k < HH) {
                const float* src = (m == 0) ? Whh0 : ((m == 1) ? Wih1 : Whh1);
                w = src[grow * HH + k];
              } else if (k < 208 && m == 0 && q3 < 2) {
                w = Wih0[grow * 8 + (k - HH)];   // fold Wih0 into r,z rows
              }
            }
          }
          const ushort hi = f2bfu(w);
          const ushort lo = f2bfu(w - bfu2f(hi));
          vh[j] = (short)hi; vl[j] = (short)lo;
        }
      }
      Ah[tt][kt] = vh; Al[tt][kt] = vl;
    }
  }

  // ---- one-time: LDS tables + zero hB (pad regions must be finite/zero) ----
  for (int u = tid; u < 2 * NBB * KP; u += 256) (&hB[0][0][0])[u] = 0;
  for (int u = tid; u < 2 * hs; u += 256) {
    const int q3 = u / hs, jj = u - q3 * hs;
    const int grow = q3 * HH + j0 + jj;
    bs0rz[u] = bih0[grow] + bhh0[grow];
    bs1rz[u] = bih1[grow] + bhh1[grow];
  }
  for (int u = tid; u < hs; u += 256) {
    const int grow = 2 * HH + j0 + u;
    b0ni[u] = bih0[grow]; b0nh[u] = bhh0[grow];
    b1ni[u] = bih1[grow]; b1nh[u] = bhh1[grow];
  }
  for (int u = tid; u < hs * 8; u += 256) {
    const int jj = u >> 3, c = u & 7;
    Wi0n[jj][c] = Wih0[(2 * HH + j0 + jj) * 8 + c];
  }
  if (tid < 4) bfcs[tid] = bfc[tid];

  // ---- staging map: u = tid + 256i over [0,3200) = [st][b 8][k 200] ----
  int boff[13], lofs[13]; uint stm = 0;
  #pragma unroll
  for (int i = 0; i < 13; ++i) {
    const int u = tid + i * 256;
    if (u < 3200) {
      const int st = (u >= 1600) ? 1 : 0;
      const int rem = u - st * 1600;
      const int b = rem / 200, k = rem - b * 200;
      boff[i] = (b0 + b) * HH + k;
      lofs[i] = (st * NBB + b) * KP + k;
      if (st) stm |= (1u << i);
    } else { boff[i] = 0; lofs[i] = 0; }
  }
  uint* const hBf = &hB[0][0][0];

  const int cj = tid & 15;          // gate: hidden index within slice
  const int cb = tid >> 4;          // gate: batch (valid < 8)
  const bool gateAct = (cj < hs) && (cb < 8);

  __syncthreads();

  for (int t = 0; t <= TT + 1; ++t) {
    // ================= staging: poll-retry LLC loads, then LDS =================
    const uint e0 = (uint)(((t - 1) >> 1) & 1);
    const uint e1 = (uint)(((t - 2) >> 1) & 1);
    const uint* h0s = h0g + ((t + 1) & 1) * HBUF;   // h0(t-1)
    const uint* h1s = h1g + (t & 1) * HBUF;         // h1(t-2)
    const bool chk0 = (t <= TT);                    // h0(TT) never written
    uint v[13];
    #pragma unroll
    for (int i = 0; i < 13; ++i)
      if (i < 12 || tid < 128)
        v[i] = llc_load_u32((((stm >> i) & 1) ? h1s : h0s) + boff[i]);
    for (;;) {
      bool ok = true;
      #pragma unroll
      for (int i = 0; i < 13; ++i)
        if (i < 12 || tid < 128) {
          const bool st = (stm >> i) & 1;
          if (st || chk0) ok = ok && (((v[i] >> 16) & 1u) == (st ? e1 : e0));
        }
      if (ok) break;
      #pragma unroll
      for (int i = 0; i < 13; ++i)
        if (i < 12 || tid < 128)
          v[i] = llc_load_u32((((stm >> i) & 1) ? h1s : h0s) + boff[i]);
    }
    #pragma unroll
    for (int i = 0; i < 13; ++i)
      if (i < 12 || tid < 128) hBf[lofs[i]] = v[i];

    if (tid < 64 && t < TT) {       // x(t) = [teacher-forced tf ; emotion]
      const int b = tid >> 3, c = tid & 7;
      float xv;
      if (c < 4) xv = (t == 0) ? 1.0f : x[((b0 + b) * TT + (t - 1)) * 8 + c];
      else       xv = x[(b0 + b) * TT * 8 + c];
      xc[t & 1][b][c] = xv;
      hB[0][b][HH + c] = packf_nt(xv);   // K-extension rows 200..207
    }
    __syncthreads();   // bar1

    // blend values for gates (read before anyone re-stages hB)
    float hv0 = 0.f, hv1 = 0.f;
    if (gateAct) {
      hv0 = upk(hB[0][cb][j0 + cj]);
      hv1 = upk(hB[1][cb][j0 + cj]);
    }

    // ================= MFMA: D[p][b] = W * [h;x], bf16x3 =================
    {
      const int Ta = 2 * wave, Tb = Ta + 1;
      const bool fa = isOut && (Ta == NT), fb = isOut && (Tb == NT);
      const bool va = (Ta < NT) || fa, vb = (Tb < NT) || fb;
      const int sa = (Ta < T0) ? 0 : 1, sb = (Tb < T0) ? 0 : 1;
      f32x4 acc0 = {0.f,0.f,0.f,0.f}, acc1 = {0.f,0.f,0.f,0.f};
      const uint* rowp = &hB[0][m15 & 7][0];
      #pragma unroll
      for (int st = 0; st < 2; ++st) {
        const bool nA = va && (sa == st), nB = vb && (sb == st);
        if (!(nA || nB)) continue;
        const uint* rp = rowp + st * (NBB * KP);
        short8 Bh[7], Bl[7];
        #pragma unroll
        for (int kt = 0; kt < 7; ++kt) {
          const uint4 u0 = *(const uint4*)&rp[kt * 32 + q * 8];
          const uint4 u1 = *(const uint4*)&rp[kt * 32 + q * 8 + 4];
          union { uint u[4]; short8 s; } ch, cl;
          ch.u[0] = __builtin_amdgcn_perm(u0.y, u0.x, 0x05040100u);
          ch.u[1] = __builtin_amdgcn_perm(u0.w, u0.z, 0x05040100u);
          ch.u[2] = __builtin_amdgcn_perm(u1.y, u1.x, 0x05040100u);
          ch.u[3] = __builtin_amdgcn_perm(u1.w, u1.z, 0x05040100u);
          cl.u[0] = __builtin_amdgcn_perm(u0.y, u0.x, 0x07060302u);
          cl.u[1] = __builtin_amdgcn_perm(u0.w, u0.z, 0x07060302u);
          cl.u[2] = __builtin_amdgcn_perm(u1.y, u1.x, 0x07060302u);
          cl.u[3] = __builtin_amdgcn_perm(u1.w, u1.z, 0x07060302u);
          Bh[kt] = ch.s; Bl[kt] = cl.s;
        }
        if (nA) {
          #pragma unroll
          for (int kt = 0; kt < 7; ++kt) {
            acc0 = __builtin_amdgcn_mfma_f32_16x16x32_bf16(Ah[0][kt], Bh[kt], acc0, 0, 0, 0);
            acc0 = __builtin_amdgcn_mfma_f32_16x16x32_bf16(Ah[0][kt], Bl[kt], acc0, 0, 0, 0);
            acc0 = __builtin_amdgcn_mfma_f32_16x16x32_bf16(Al[0][kt], Bh[kt], acc0, 0, 0, 0);
          }
        }
        if (nB) {
          #pragma unroll
          for (int kt = 0; kt < 7; ++kt) {
            acc1 = __builtin_amdgcn_mfma_f32_16x16x32_bf16(Ah[1][kt], Bh[kt], acc1, 0, 0, 0);
            acc1 = __builtin_amdgcn_mfma_f32_16x16x32_bf16(Ah[1][kt], Bl[kt], acc1, 0, 0, 0);
            acc1 = __builtin_amdgcn_mfma_f32_16x16x32_bf16(Al[1][kt], Bh[kt], acc1, 0, 0, 0);
          }
        }
      }
      if (m15 < 8) {
        if (va) {
          #pragma unroll
          for (int i = 0; i < 4; ++i) D[Ta * 16 + q * 4 + i][m15] = acc0[i];
        }
        if (vb) {
          #pragma unroll
          for (int i = 0; i < 4; ++i) D[Tb * 16 + q * 4 + i][m15] = acc1[i];
        }
      }
    }
    __syncthreads();   // bar2

    // ================= gates + tagged LLC stores =================
    if (gateAct) {
      if (t < TT) {                 // h0(t)
        const float sr = D[cj][cb] + bs0rz[cj];
        const float sz = D[hs + cj][cb] + bs0rz[hs + cj];
        const float hn = D[2 * hs + cj][cb] + b0nh[cj];
        float in0 = b0ni[cj];
        #pragma unroll
        for (int c = 0; c < 8; ++c) in0 += Wi0n[cj][c] * xc[t & 1][cb][c];
        const float r = sigm(sr), z = sigm(sz);
        const float n = tanh_fast(in0 + r * hn);
        llc_store_u32(h0g + (t & 1) * HBUF + (b0 + cb) * HH + (j0 + cj),
                      packf_tag((1.0f - z) * n + z * hv0, (uint)((t >> 1) & 1)));
      }
      if (t >= 1 && t <= TT) {      // h1(t-1)
        const int pd = T0 * 16 + cj;
        const float sr  = D[3 * hs + cj][cb] + D[pd][cb] + bs1rz[cj];
        const float sz  = D[4 * hs + cj][cb] + D[pd + hs][cb] + bs1rz[hs + cj];
        const float in1 = D[5 * hs + cj][cb] + b1ni[cj];
        const float hn1 = D[pd + 2 * hs][cb] + b1nh[cj];
        const float r = sigm(sr), z = sigm(sz);
        const float n = tanh_fast(in1 + r * hn1);
        llc_store_u32(h1g + ((t + 1) & 1) * HBUF + (b0 + cb) * HH + (j0 + cj),
                      packf_tag((1.0f - z) * n + z * hv1, (uint)(((t - 1) >> 1) & 1)));
      }
    }
    if (isOut && t >= 2 && tid < 32) {   // out(t-2) from FC tile (p=48..51)
      const int oo = tid & 3, ob = tid >> 2;
      out[((b0 + ob) * TT + (t - 2)) * 4 + oo] = tanh_fast(D[48 + oo][ob] + bfcs[oo]);
    }
  }
}

extern "C" void kernel_launch(void* const* d_in, const int* in_sizes, int n_in,
                              void* d_out, int out_size, void* d_ws, size_t ws_size,
                              hipStream_t stream) {
  uint* ws = (uint*)d_ws;
  // ws (u32): h0g[2][128][200] @0, h1g[2][128][200] @51200.
  init_state<<<400, 256, 0, stream>>>(ws);
  gru2_tag<<<256, 256, 0, stream>>>(
      (const float*)d_in[0],
      (const float*)d_in[1], (const float*)d_in[2],
      (const float*)d_in[3], (const float*)d_in[4],
      (const float*)d_in[5], (const float*)d_in[6],
      (const float*)d_in[7], (const float*)d_in[8],
      (const float*)d_in[9], (const float*)d_in[10],
      (float*)d_out, ws, ws + 2 * HBUF);
}

// Round 5
// 5777.150 us; speedup vs baseline: 1.0811x; 1.0811x over previous
//
#include <hip/hip_runtime.h>
#include <hip/hip_bf16.h>

// 2-layer GRU decoder, persistent MFMA kernel. B=128, T=1024, H=200.
// R5 = R3 skeleton (NB=16, 8 groups x 16 slices = 128 blocks, barrier/step)
// with three fixes:
//  - h staged in LDS in MFMA B-FRAGMENT ORDER (lane-contiguous 16B) -> stride-1
//    conflict-free ds_read_b128; hi/lo planes separate (no perm unpack).
//  - B fragments shared across a wave's two same-state tiles: 70 b128/block-step.
//  - Sync via 16-flag LLC line per group (flag[s] = t+1, monotonic): no atomic
//    RMW serialization; wave0 polls one 64B line, then ONE bulk h load.
//    (R4's per-dword tag retry loop regressed 2x: serial full-latency reload
//    rounds + fabric congestion. Reverted.)

#define TT   1024
#define HH   200
#define NB   16
#define HS   13
#define HBUF 25600           // one h buffer: 128*200 u32
#define PST  3584            // plane stride per state: 7 kt * 512 ushorts

typedef __attribute__((ext_vector_type(8))) short short8;
typedef __attribute__((ext_vector_type(4))) float f32x4;

__device__ __forceinline__ float sigm(float v) { return 1.0f / (1.0f + __expf(-v)); }
__device__ __forceinline__ float tanh_fast(float v) {
  float e = __expf(-2.0f * v);
  return (1.0f - e) / (1.0f + e);
}
__device__ __forceinline__ uint llc_load_u32(const uint* p) {
  return __hip_atomic_load(p, __ATOMIC_RELAXED, __HIP_MEMORY_SCOPE_SYSTEM);
}
__device__ __forceinline__ void llc_store_u32(uint* p, uint v) {
  __hip_atomic_store(p, v, __ATOMIC_RELAXED, __HIP_MEMORY_SCOPE_SYSTEM);
}
__device__ __forceinline__ float bfu2f(ushort u) { return __uint_as_float(((uint)u) << 16); }
__device__ __forceinline__ ushort f2bfu(float f) {
  __hip_bfloat16 b = __float2bfloat16(f);
  return *(ushort*)&b;
}
__device__ __forceinline__ uint packf(float h) {   // (hi | lo<<16) bf16 pair
  ushort hi = f2bfu(h);
  ushort lo = f2bfu(h - bfu2f(hi));
  return (uint)hi | (((uint)lo) << 16);
}

__global__ __launch_bounds__(256, 1) void gru2_frag(
    const float* __restrict__ x,
    const float* __restrict__ Wih0, const float* __restrict__ Whh0,
    const float* __restrict__ bih0, const float* __restrict__ bhh0,
    const float* __restrict__ Wih1, const float* __restrict__ Whh1,
    const float* __restrict__ bih1, const float* __restrict__ bhh1,
    const float* __restrict__ Wfc,  const float* __restrict__ bfc,
    float* __restrict__ out,
    uint* __restrict__ h0g, uint* __restrict__ h1g, uint* __restrict__ flags)
{
  // Fragment-order planes: [st][kt][lane][j] ; lane = n(batch) + 16*q, j in [0,8).
  // Element (st, b, k): kt=k/32, q=(k%32)/8, j=k%8 -> ushort idx st*PST + kt*512 + (b+16q)*8 + j.
  __shared__ __align__(16) ushort hFh[2 * PST];
  __shared__ __align__(16) ushort hFl[2 * PST];
  __shared__ float D[117][17];
  __shared__ float Wi0[39][8];
  __shared__ float bi0[39], bh0[39], bi1[39], bh1[39], bfs[4];
  __shared__ float xc[NB][8];

  const int tid  = threadIdx.x;
  const int wave = tid >> 6;
  const int lane = tid & 63;
  const int m15  = lane & 15;
  const int q    = lane >> 4;

  const int g  = blockIdx.x & 7;     // batch-group
  const int s  = blockIdx.x >> 3;    // hidden-slice
  const int b0 = g * NB;
  const int j0 = s * HS;
  const int hs = (HH - j0 < HS) ? (HH - j0) : HS;   // 13, or 5 for s==15
  const int th  = 3 * hs;
  const int h0r = 6 * hs;                            // r-space rows dotted with h0
  const int T0  = (h0r + 15) >> 4;                   // 5 / 2
  const int NT  = T0 + ((th + 15) >> 4);             // 8 / 3
  const bool isOut = (s == 15);

  // ---- one-time: weight A-fragments into registers (hi/lo bf16) ----
  // r-space: [0,3hs)=Whh0 r,z,n ; [3hs,6hs)=Wih1 r,z,n ; [6hs,9hs)=Whh1 r,z,n.
  // Tile T covers p-rows [16T,16T+16): p<h0r -> r=p ; p-T0*16 in [0,th) -> r=h0r+(p-T0*16).
  short8 Ah[2][7], Al[2][7];
  #pragma unroll
  for (int tt = 0; tt < 2; ++tt) {
    const int T = 2 * wave + tt;
    const bool isFC = isOut && (T == NT);
    const bool val  = (T < NT) || isFC;
    #pragma unroll
    for (int kt = 0; kt < 7; ++kt) {
      short8 vh = {0,0,0,0,0,0,0,0}, vl = {0,0,0,0,0,0,0,0};
      if (val) {
        #pragma unroll
        for (int j = 0; j < 8; ++j) {
          const int k = kt * 32 + q * 8 + j;
          float w = 0.0f;
          if (k < HH) {
            if (isFC) {
              if (m15 < 4) w = Wfc[m15 * HH + k];
            } else {
              const int p = T * 16 + m15;
              int r = -1;
              if (p < h0r) r = p;
              else { const int pp = p - T0 * 16; if (pp >= 0 && pp < th) r = h0r + pp; }
              if (r >= 0) {
                const int m = r / th, rr = r - m * th;
                const int q3 = rr / hs, jj = rr - q3 * hs;
                const float* src = (m == 0) ? Whh0 : ((m == 1) ? Wih1 : Whh1);
                w = src[(q3 * HH + j0 + jj) * HH + k];
              }
            }
          }
          const ushort hi = f2bfu(w);
          const ushort lo = f2bfu(w - bfu2f(hi));
          vh[j] = (short)hi; vl[j] = (short)lo;
        }
      }
      Ah[tt][kt] = vh; Al[tt][kt] = vl;
    }
  }

  // ---- one-time: LDS tables; zero planes (k>=200 pad must stay 0) ----
  for (int u = tid; u < 2 * PST; u += 256) { hFh[u] = 0; hFl[u] = 0; }
  for (int u = tid; u < th * 8; u += 256) {
    const int rr = u >> 3, c = u & 7;
    const int q3 = rr / hs, jj = rr - q3 * hs;
    Wi0[rr][c] = Wih0[(q3 * HH + j0 + jj) * 8 + c];
  }
  for (int u = tid; u < th; u += 256) {
    const int q3 = u / hs, jj = u - q3 * hs;
    const int grow = q3 * HH + j0 + jj;
    bi0[u] = bih0[grow]; bh0[u] = bhh0[grow];
    bi1[u] = bih1[grow]; bh1[u] = bhh1[grow];
  }
  if (tid < 4) bfs[tid] = bfc[tid];

  // ---- staging map precompute: u = tid + 256*i over [0,6400) ----
  // b = u&15 ; v2 = u>>4 in [0,400) ; st = v2>=200 ; k = v2 - 200*st.
  int boff[25], lofs[25]; uint stm = 0;
  #pragma unroll
  for (int i = 0; i < 25; ++i) {
    const int u  = tid + i * 256;
    const int b  = u & 15;
    const int v2 = u >> 4;
    const int st = (v2 >= 200) ? 1 : 0;
    const int k  = v2 - st * 200;
    const int kt = k >> 5, r32 = k & 31, qq = r32 >> 3, j = r32 & 7;
    boff[i] = (b0 + b) * HH + k;
    lofs[i] = st * PST + kt * 512 + (b + 16 * qq) * 8 + j;
    if (st) stm |= (1u << i);
  }

  // gate-combine indices + plane index of this thread's own h element
  const int cj = tid >> 4, cb = tid & 15;
  const bool gAct = (cj < hs);
  int hvix = 0;
  if (gAct) {
    const int k = j0 + cj;
    const int kt = k >> 5, r32 = k & 31, qq = r32 >> 3, j = r32 & 7;
    hvix = kt * 512 + (cb + 16 * qq) * 8 + j;
  }

  uint* const flg = flags + g * 32;   // 16 flags in one 64B line, 128B group stride
  __syncthreads();

  for (int t = 0; t <= TT + 1; ++t) {
    // ---- x(t) staging (independent of flags; xc safe: last read pre-bar3) ----
    if (tid < 128 && t < TT) {
      const int b = tid >> 3, c = tid & 7;
      float v;
      if (c < 4) v = (t == 0) ? 1.0f : x[((b0 + b) * TT + (t - 1)) * 8 + c];
      else       v = x[(b0 + b) * TT * 8 + c];     // emotion = x[b][0][4..7]
      xc[b][c] = v;
    }

    // ---- wait: all 16 producer flags >= t (their step t-1 stores visible) ----
    if (wave == 0) {
      const uint tgt = (uint)t;
      for (;;) {
        const uint f = (lane < 16) ? llc_load_u32(flg + lane) : tgt;
        if (__all((int)(f >= tgt))) break;
        __builtin_amdgcn_s_sleep(2);
      }
    }
    __syncthreads();

    // ---- bulk h load (once) -> fragment-order LDS planes ----
    const uint* h0s = h0g + ((t + 1) & 1) * HBUF;   // h0(t-1)
    const uint* h1s = h1g + (t & 1) * HBUF;         // h1(t-2)
    uint v[25];
    #pragma unroll
    for (int i = 0; i < 25; ++i)
      v[i] = llc_load_u32((((stm >> i) & 1) ? h1s : h0s) + boff[i]);
    #pragma unroll
    for (int i = 0; i < 25; ++i) {
      hFh[lofs[i]] = (ushort)(v[i] & 0xffffu);
      hFl[lofs[i]] = (ushort)(v[i] >> 16);
    }
    __syncthreads();   // bar1

    // ---- MFMA: bf16x3, B fragments shared across the wave's same-st tiles ----
    {
      const int  Ta = 2 * wave, Tb = Ta + 1;
      const bool fa = isOut && (Ta == NT);
      const bool fb = isOut && (Tb == NT);
      const bool va = (Ta < NT) || fa, vb = (Tb < NT) || fb;
      const int  sa = (fa || Ta >= T0) ? 1 : 0;
      const int  sb = (fb || Tb >= T0) ? 1 : 0;
      f32x4 acc0 = {0.f,0.f,0.f,0.f}, acc1 = {0.f,0.f,0.f,0.f};
      const int lb = lane * 8;
      #pragma unroll
      for (int st = 0; st < 2; ++st) {
        const bool nA = va && (sa == st), nB = vb && (sb == st);
        if (!(nA || nB)) continue;
        const ushort* bh = hFh + st * PST + lb;
        const ushort* bl = hFl + st * PST + lb;
        #pragma unroll
        for (int kt = 0; kt < 7; ++kt) {
          const short8 Bh = *(const short8*)(bh + kt * 512);
          const short8 Bl = *(const short8*)(bl + kt * 512);
          if (nA) {
            acc0 = __builtin_amdgcn_mfma_f32_16x16x32_bf16(Ah[0][kt], Bh, acc0, 0, 0, 0);
            acc0 = __builtin_amdgcn_mfma_f32_16x16x32_bf16(Ah[0][kt], Bl, acc0, 0, 0, 0);
            acc0 = __builtin_amdgcn_mfma_f32_16x16x32_bf16(Al[0][kt], Bh, acc0, 0, 0, 0);
          }
          if (nB) {
            acc1 = __builtin_amdgcn_mfma_f32_16x16x32_bf16(Ah[1][kt], Bh, acc1, 0, 0, 0);
            acc1 = __builtin_amdgcn_mfma_f32_16x16x32_bf16(Ah[1][kt], Bl, acc1, 0, 0, 0);
            acc1 = __builtin_amdgcn_mfma_f32_16x16x32_bf16(Al[1][kt], Bh, acc1, 0, 0, 0);
          }
        }
      }
      if (va && !fa) {
        #pragma unroll
        for (int i = 0; i < 4; ++i) {
          const int p = Ta * 16 + q * 4 + i;
          int r = -1;
          if (p < h0r) r = p;
          else { const int pp = p - T0 * 16; if (pp >= 0 && pp < th) r = h0r + pp; }
          if (r >= 0) D[r][m15] = acc0[i];
        }
      }
      if (vb && !fb) {
        #pragma unroll
        for (int i = 0; i < 4; ++i) {
          const int p = Tb * 16 + q * 4 + i;
          int r = -1;
          if (p < h0r) r = p;
          else { const int pp = p - T0 * 16; if (pp >= 0 && pp < th) r = h0r + pp; }
          if (r >= 0) D[r][m15] = acc1[i];
        }
      }
      if (fb && t >= 2) {     // FC head: out(t-2) = tanh(Wfc h1(t-2) + bfc)
        #pragma unroll
        for (int i = 0; i < 4; ++i) {
          const int p = q * 4 + i;
          if (p < 4)
            out[((b0 + m15) * TT + (t - 2)) * 4 + p] = tanh_fast(acc1[i] + bfs[p]);
        }
      }
    }
    __syncthreads();   // bar2

    // ---- gates + packed LLC stores ----
    if (gAct) {
      const float hv0 = bfu2f(hFh[hvix]) + bfu2f(hFl[hvix]);
      const float hv1 = bfu2f(hFh[PST + hvix]) + bfu2f(hFl[PST + hvix]);
      if (t < TT) {                 // h0(t)
        float ir = bi0[cj], iz = bi0[hs + cj], in_ = bi0[2 * hs + cj];
        #pragma unroll
        for (int c = 0; c < 8; ++c) {
          const float xv = xc[cb][c];
          ir  += Wi0[cj][c] * xv;
          iz  += Wi0[hs + cj][c] * xv;
          in_ += Wi0[2 * hs + cj][c] * xv;
        }
        const float hr = D[cj][cb] + bh0[cj];
        const float hz = D[hs + cj][cb] + bh0[hs + cj];
        const float hn = D[2 * hs + cj][cb] + bh0[2 * hs + cj];
        const float r = sigm(ir + hr), z = sigm(iz + hz);
        const float n = tanh_fast(in_ + r * hn);
        llc_store_u32(h0g + (t & 1) * HBUF + (b0 + cb) * HH + (j0 + cj),
                      packf((1.0f - z) * n + z * hv0));
      }
      if (t >= 1 && t <= TT) {      // h1(t-1)
        const float ir  = D[3 * hs + cj][cb] + bi1[cj];
        const float iz  = D[4 * hs + cj][cb] + bi1[hs + cj];
        const float in_ = D[5 * hs + cj][cb] + bi1[2 * hs + cj];
        const float hr  = D[6 * hs + cj][cb] + bh1[cj];
        const float hz  = D[7 * hs + cj][cb] + bh1[hs + cj];
        const float hn  = D[8 * hs + cj][cb] + bh1[2 * hs + cj];
        const float r = sigm(ir + hr), z = sigm(iz + hz);
        const float n = tanh_fast(in_ + r * hn);
        llc_store_u32(h1g + ((t + 1) & 1) * HBUF + (b0 + cb) * HH + (j0 + cj),
                      packf((1.0f - z) * n + z * hv1));
      }
    }

    // ---- signal: drain stores (syncthreads waits vmcnt(0)) then flag=t+1 ----
    __syncthreads();   // bar3: also orders plane/xc reads before next staging
    if (tid == 0) llc_store_u32(flg + s, (uint)(t + 1));
  }
}

extern "C" void kernel_launch(void* const* d_in, const int* in_sizes, int n_in,
                              void* d_out, int out_size, void* d_ws, size_t ws_size,
                              hipStream_t stream) {
  uint* ws = (uint*)d_ws;
  // ws (u32): h0g[2][128][200] @0, h1g[2][128][200] @2*HBUF,
  // flags 8 groups x 32 u32 stride @4*HBUF. packed h=0 is bit pattern 0 -> memset ok.
  hipMemsetAsync(d_ws, 0, (size_t)(4 * HBUF + 256) * sizeof(uint), stream);
  gru2_frag<<<128, 256, 0, stream>>>(
      (const float*)d_in[0],
      (const float*)d_in[1], (const float*)d_in[2],
      (const float*)d_in[3], (const float*)d_in[4],
      (const float*)d_in[5], (const float*)d_in[6],
      (const float*)d_in[7], (const float*)d_in[8],
      (const float*)d_in[9], (const float*)d_in[10],
      (float*)d_out, ws, ws + 2 * HBUF, ws + 4 * HBUF);
}

// Round 6
// 3580.537 us; speedup vs baseline: 1.7444x; 1.6135x over previous
//
#include <hip/hip_runtime.h>
#include <hip/hip_bf16.h>

// 2-layer GRU decoder, persistent MFMA kernel. B=128, T=1024, H=200.
// R6 = R3 EXACT SKELETON (8 groups x 16 slices = 128 blocks, NB=16,
// hBh/hBl[st][b][k] LDS planes, atomic-counter barrier) + two local changes:
//  (1) staging indices precomputed into registers (R3 recomputed div/mod per step)
//  (2) B-fragment ds_reads shared across a wave's two same-state tiles
// Everything else (sync, layout, staging order, gates, FC) is R3 verbatim.
// R4 (tag sync) and R5 (frag-order LDS + flag-line sync) both regressed ~1.8x
// with identical total VALU/MFMA cycles -> unexplained dead time; bisecting.

#define TT 1024
#define HH 200
#define NB 16
#define HS 13
#define KP 232   // hB row stride in ushorts; 464 B = 29*16 -> b128-aligned

typedef __attribute__((ext_vector_type(8))) short short8;
typedef __attribute__((ext_vector_type(4))) float f32x4;

__device__ __forceinline__ float sigm(float v) { return 1.0f / (1.0f + __expf(-v)); }
__device__ __forceinline__ float tanh_fast(float v) {
  float e = __expf(-2.0f * v);
  return (1.0f - e) / (1.0f + e);
}
__device__ __forceinline__ uint llc_load_u32(const uint* p) {
  return __hip_atomic_load(p, __ATOMIC_RELAXED, __HIP_MEMORY_SCOPE_SYSTEM);
}
__device__ __forceinline__ void llc_store_u32(uint* p, uint v) {
  __hip_atomic_store(p, v, __ATOMIC_RELAXED, __HIP_MEMORY_SCOPE_SYSTEM);
}
__device__ __forceinline__ float bfu2f(ushort u) { return __uint_as_float(((uint)u) << 16); }
__device__ __forceinline__ ushort f2bfu(float f) {
  __hip_bfloat16 b = __float2bfloat16(f);
  return *(ushort*)&b;
}
__device__ __forceinline__ uint packf(float h) {
  ushort hi = f2bfu(h);
  ushort lo = f2bfu(h - bfu2f(hi));
  return (uint)hi | (((uint)lo) << 16);
}

__global__ __launch_bounds__(256, 1) void gru2_mfma(
    const float* __restrict__ x,
    const float* __restrict__ Wih0, const float* __restrict__ Whh0,
    const float* __restrict__ bih0, const float* __restrict__ bhh0,
    const float* __restrict__ Wih1, const float* __restrict__ Whh1,
    const float* __restrict__ bih1, const float* __restrict__ bhh1,
    const float* __restrict__ Wfc,  const float* __restrict__ bfc,
    float* __restrict__ out,
    uint* __restrict__ h0g, uint* __restrict__ h1g, int* __restrict__ bars)
{
  __shared__ __align__(16) ushort hBh[2][NB][KP];
  __shared__ __align__(16) ushort hBl[2][NB][KP];
  __shared__ float D[117][17];
  __shared__ float Wi0[39][8];
  __shared__ float bi0[39], bh0[39], bi1[39], bh1[39], bfs[4];
  __shared__ float xc[NB][8];

  const int tid  = threadIdx.x;
  const int wave = tid >> 6;
  const int lane = tid & 63;
  const int m15  = lane & 15;
  const int q    = lane >> 4;

  const int g  = blockIdx.x & 7;    // batch-group
  const int s  = blockIdx.x >> 3;   // hidden-slice
  const int b0 = g * NB;
  const int j0 = s * HS;
  const int hs = (HH - j0 < HS) ? (HH - j0) : HS;   // 13 (s<15) or 5 (s==15)
  const int th   = 3 * hs;
  const int h0r  = 6 * hs;                          // rows dotted with h0
  const int T0   = (h0r + 15) >> 4;                 // 5 or 2  (h0 tiles)
  const int NT   = T0 + ((th + 15) >> 4);           // 8 or 3  (total tiles)
  const bool isOut = (s == 15);

  // ---- one-time: weight A-fragments into registers (hi/lo bf16) ----
  short8 Ah[2][7], Al[2][7];
  #pragma unroll
  for (int mt = 0; mt < 2; ++mt) {
    const int T = wave * 2 + mt;
    const bool fc  = isOut && (wave == 2) && (mt == 0);
    const bool val = fc || (T < NT);
    #pragma unroll
    for (int kt = 0; kt < 7; ++kt) {
      short8 vh = {0,0,0,0,0,0,0,0}, vl = {0,0,0,0,0,0,0,0};
      #pragma unroll
      for (int j = 0; j < 8; ++j) {
        const int k = kt * 32 + q * 8 + j;
        float w = 0.0f;
        if (val && k < HH) {
          if (fc) {
            if (m15 < 4) w = Wfc[m15 * HH + k];
          } else {
            const int p = T * 16 + m15;
            int r = -1;
            if (p < h0r) r = p;
            else if (p >= T0 * 16 && (p - T0 * 16) < th) r = h0r + (p - T0 * 16);
            if (r >= 0) {
              const int m  = r / th, rr = r - m * th;
              const int qq = rr / hs, jj = rr - qq * hs;
              const float* src = (m == 0) ? Whh0 : ((m == 1) ? Wih1 : Whh1);
              w = src[(qq * HH + j0 + jj) * HH + k];
            }
          }
        }
        const ushort uh = f2bfu(w);
        const ushort ul = f2bfu(w - bfu2f(uh));
        vh[j] = (short)uh; vl[j] = (short)ul;
      }
      Ah[mt][kt] = vh; Al[mt][kt] = vl;
    }
  }

  // ---- one-time: small LDS tables ----
  for (int u = tid; u < th * 8; u += 256) {
    int rr = u >> 3, c = u & 7;
    int qq = rr / hs, jj = rr - qq * hs;
    Wi0[rr][c] = Wih0[(qq * HH + j0 + jj) * 8 + c];
  }
  for (int u = tid; u < th; u += 256) {
    int qq = u / hs, jj = u - qq * hs;
    int grow = qq * HH + j0 + jj;
    bi0[u] = bih0[grow]; bh0[u] = bhh0[grow];
    bi1[u] = bih1[grow]; bh1[u] = bhh1[grow];
  }
  if (tid < 4) bfs[tid] = bfc[tid];
  for (int u = tid; u < 2 * NB * KP / 2; u += 256) ((uint*)hBh)[u] = 0;  // zero pads
  for (int u = tid; u < 2 * NB * KP / 2; u += 256) ((uint*)hBl)[u] = 0;
  __syncthreads();

  // ---- (R6.1) staging map precompute: u = tid + 256*i over [0,6400) ----
  // R3 mapping kept: st = u/3200, b = rem/200, k = rem%200.
  int boff[25], lofs[25]; uint stm = 0;
  #pragma unroll
  for (int i = 0; i < 25; ++i) {
    const int u   = tid + i * 256;
    const int st  = (u >= 3200) ? 1 : 0;
    const int rem = u - st * 3200;
    const int b   = rem / 200;
    const int k   = rem - b * 200;
    boff[i] = (b0 + b) * HH + k;
    lofs[i] = (st * NB + b) * KP + k;
    if (st) stm |= (1u << i);
  }
  ushort* const hBhF = &hBh[0][0][0];
  ushort* const hBlF = &hBl[0][0][0];

  int* bar = &bars[g * 64];
  const int cj = tid >> 4, cb = tid & 15;   // gate-combine indices

  for (int t = 0; t <= TT + 1; ++t) {
    // ---- stage h0(t-1), h1(t-2): packed bf16 hi/lo from LLC -> LDS planes ----
    const uint* h0src = h0g + ((t + 1) & 1) * (128 * HH);
    const uint* h1src = h1g + (t & 1) * (128 * HH);
    uint v[25];
    #pragma unroll
    for (int i = 0; i < 25; ++i)
      v[i] = llc_load_u32((((stm >> i) & 1) ? h1src : h0src) + boff[i]);
    #pragma unroll
    for (int i = 0; i < 25; ++i) {
      hBhF[lofs[i]] = (ushort)(v[i] & 0xffffu);
      hBlF[lofs[i]] = (ushort)(v[i] >> 16);
    }
    if (tid < 128 && t < TT) {             // inputs for h0(t): tf + emotion
      int b = tid >> 3, c = tid & 7;
      float xv;
      if (c < 4) xv = (t == 0) ? 1.0f : x[((b0 + b) * TT + (t - 1)) * 8 + c];
      else       xv = x[(b0 + b) * TT * 8 + c];
      xc[b][c] = xv;
    }
    __syncthreads();

    // ---- MFMA: D[rows x 16 batch] = W * h, bf16x3; (R6.2) B shared per st ----
    {
      const int  Ta = 2 * wave, Tb = Ta + 1;
      const bool fa = isOut && (wave == 2);        // FC tile = wave2/mt0 (R3)
      const bool va = (Ta < NT) || fa;
      const bool vb = (Tb < NT);
      const int  sa = fa ? 1 : ((Ta < T0) ? 0 : 1);
      const int  sb = (Tb < T0) ? 0 : 1;
      f32x4 acc0 = {0.f,0.f,0.f,0.f}, acc1 = {0.f,0.f,0.f,0.f};
      #pragma unroll
      for (int st = 0; st < 2; ++st) {
        const bool nA = va && (sa == st), nB = vb && (sb == st);
        if (!(nA || nB)) continue;
        const ushort* bh = &hBh[st][m15][0];
        const ushort* bl = &hBl[st][m15][0];
        #pragma unroll
        for (int kt = 0; kt < 7; ++kt) {
          const short8 Bh = *(const short8*)(bh + kt * 32 + q * 8);
          const short8 Bl = *(const short8*)(bl + kt * 32 + q * 8);
          if (nA) {
            acc0 = __builtin_amdgcn_mfma_f32_16x16x32_bf16(Ah[0][kt], Bh, acc0, 0, 0, 0);
            acc0 = __builtin_amdgcn_mfma_f32_16x16x32_bf16(Ah[0][kt], Bl, acc0, 0, 0, 0);
            acc0 = __builtin_amdgcn_mfma_f32_16x16x32_bf16(Al[0][kt], Bh, acc0, 0, 0, 0);
          }
          if (nB) {
            acc1 = __builtin_amdgcn_mfma_f32_16x16x32_bf16(Ah[1][kt], Bh, acc1, 0, 0, 0);
            acc1 = __builtin_amdgcn_mfma_f32_16x16x32_bf16(Ah[1][kt], Bl, acc1, 0, 0, 0);
            acc1 = __builtin_amdgcn_mfma_f32_16x16x32_bf16(Al[1][kt], Bh, acc1, 0, 0, 0);
          }
        }
      }
      if (fa) {                              // FC head: out(t-2)
        if (t >= 2) {
          #pragma unroll
          for (int i = 0; i < 4; ++i) {
            const int p = q * 4 + i;
            if (p < 4)
              out[((b0 + m15) * TT + (t - 2)) * 4 + p] = tanh_fast(acc0[i] + bfs[p]);
          }
        }
      } else if (va) {
        #pragma unroll
        for (int i = 0; i < 4; ++i) {
          const int p = Ta * 16 + q * 4 + i;
          int r = -1;
          if (p < h0r) r = p;
          else if (p >= T0 * 16 && (p - T0 * 16) < th) r = h0r + (p - T0 * 16);
          if (r >= 0) D[r][m15] = acc0[i];
        }
      }
      if (vb) {
        #pragma unroll
        for (int i = 0; i < 4; ++i) {
          const int p = Tb * 16 + q * 4 + i;
          int r = -1;
          if (p < h0r) r = p;
          else if (p >= T0 * 16 && (p - T0 * 16) < th) r = h0r + (p - T0 * 16);
          if (r >= 0) D[r][m15] = acc1[i];
        }
      }
    }
    __syncthreads();

    // ---- gate combine + state update (packed stores to LLC) ----
    if (cj < hs) {
      const float hv0 = bfu2f(hBh[0][cb][j0 + cj]) + bfu2f(hBl[0][cb][j0 + cj]);
      const float hv1 = bfu2f(hBh[1][cb][j0 + cj]) + bfu2f(hBl[1][cb][j0 + cj]);
      if (t < TT) {                 // h0(t)
        float ir = bi0[cj], iz = bi0[hs + cj], in_ = bi0[2 * hs + cj];
        #pragma unroll
        for (int c = 0; c < 8; ++c) {
          const float xv = xc[cb][c];
          ir  += Wi0[cj][c] * xv;
          iz  += Wi0[hs + cj][c] * xv;
          in_ += Wi0[2 * hs + cj][c] * xv;
        }
        const float hr = D[cj][cb] + bh0[cj];
        const float hz = D[hs + cj][cb] + bh0[hs + cj];
        const float hn = D[2 * hs + cj][cb] + bh0[2 * hs + cj];
        const float r = sigm(ir + hr), z = sigm(iz + hz);
        const float n = tanh_fast(in_ + r * hn);
        llc_store_u32(&h0g[(t & 1) * (128 * HH) + (b0 + cb) * HH + j0 + cj],
                      packf((1.0f - z) * n + z * hv0));
      }
      if (t >= 1 && t <= TT) {      // h1(t-1)
        const float ir  = D[3 * hs + cj][cb] + bi1[cj];
        const float iz  = D[4 * hs + cj][cb] + bi1[hs + cj];
        const float in_ = D[5 * hs + cj][cb] + bi1[2 * hs + cj];
        const float hr  = D[6 * hs + cj][cb] + bh1[cj];
        const float hz  = D[7 * hs + cj][cb] + bh1[hs + cj];
        const float hn  = D[8 * hs + cj][cb] + bh1[2 * hs + cj];
        const float r = sigm(ir + hr), z = sigm(iz + hz);
        const float n = tanh_fast(in_ + r * hn);
        llc_store_u32(&h1g[((t + 1) & 1) * (128 * HH) + (b0 + cb) * HH + j0 + cj],
                      packf((1.0f - z) * n + z * hv1));
      }
    }

    // ---- per-group barrier at the LLC (R3 verbatim) ----
    __syncthreads();   // s_waitcnt vmcnt(0) before s_barrier: stores at LLC
    if (tid == 0) {
      __hip_atomic_fetch_add(bar, 1, __ATOMIC_RELAXED, __HIP_MEMORY_SCOPE_SYSTEM);
      const int target = 16 * (t + 1);
      while (__hip_atomic_load(bar, __ATOMIC_RELAXED, __HIP_MEMORY_SCOPE_SYSTEM) < target)
        __builtin_amdgcn_s_sleep(1);
    }
    __syncthreads();
  }
}

extern "C" void kernel_launch(void* const* d_in, const int* in_sizes, int n_in,
                              void* d_out, int out_size, void* d_ws, size_t ws_size,
                              hipStream_t stream) {
  uint* ws = (uint*)d_ws;
  // ws (u32): h0g[2][128][200] @0, h1g[2][128][200] @51200,
  // barrier counters (8 x 256B-strided ints) @102400.
  hipMemsetAsync(d_ws, 0, (size_t)(102400 + 512) * sizeof(uint), stream);
  gru2_mfma<<<128, 256, 0, stream>>>(
      (const float*)d_in[0],
      (const float*)d_in[1], (const float*)d_in[2],
      (const float*)d_in[3], (const float*)d_in[4],
      (const float*)d_in[5], (const float*)d_in[6],
      (const float*)d_in[7], (const float*)d_in[8],
      (const float*)d_in[9], (const float*)d_in[10],
      (float*)d_out, ws, ws + 51200, (int*)(ws + 102400));
}

// Round 7
// 3435.369 us; speedup vs baseline: 1.8181x; 1.0423x over previous
//
#include <hip/hip_runtime.h>
#include <hip/hip_bf16.h>

// 2-layer GRU decoder, persistent MFMA kernel. B=128, T=1024, H=200.
// R7 = R6 EXACT (8 groups x 16 slices = 128 blocks, NB=16, hBh/hBl[st][b][k]
// LDS planes, coalesced staging via precomputed indices, B-frag sharing)
// with ONE change: the per-group atomic-counter barrier is replaced by a
// 16-flag LLC line (flag[s] = t+1, monotonic, one store per producer, no RMW).
// Theory: 16 fetch_adds to one LLC line from 16 CUs serialize (~1.2 us/step
// convoy); independent word-stores to one 64B line pipeline freely and the
// consumer polls with a single 16-lane load + __all.
// (R5 bundled this sync with an uncoalesced staging gather (b=u&15) -> 64-line
// gathers per load instr; that was the regressor. R6 re-established the
// coalesced baseline; R7 isolates the sync change.)

#define TT 1024
#define HH 200
#define NB 16
#define HS 13
#define KP 232   // hB row stride in ushorts; 464 B = 29*16 -> b128-aligned

typedef __attribute__((ext_vector_type(8))) short short8;
typedef __attribute__((ext_vector_type(4))) float f32x4;

__device__ __forceinline__ float sigm(float v) { return 1.0f / (1.0f + __expf(-v)); }
__device__ __forceinline__ float tanh_fast(float v) {
  float e = __expf(-2.0f * v);
  return (1.0f - e) / (1.0f + e);
}
__device__ __forceinline__ uint llc_load_u32(const uint* p) {
  return __hip_atomic_load(p, __ATOMIC_RELAXED, __HIP_MEMORY_SCOPE_SYSTEM);
}
__device__ __forceinline__ void llc_store_u32(uint* p, uint v) {
  __hip_atomic_store(p, v, __ATOMIC_RELAXED, __HIP_MEMORY_SCOPE_SYSTEM);
}
__device__ __forceinline__ float bfu2f(ushort u) { return __uint_as_float(((uint)u) << 16); }
__device__ __forceinline__ ushort f2bfu(float f) {
  __hip_bfloat16 b = __float2bfloat16(f);
  return *(ushort*)&b;
}
__device__ __forceinline__ uint packf(float h) {
  ushort hi = f2bfu(h);
  ushort lo = f2bfu(h - bfu2f(hi));
  return (uint)hi | (((uint)lo) << 16);
}

__global__ __launch_bounds__(256, 1) void gru2_mfma(
    const float* __restrict__ x,
    const float* __restrict__ Wih0, const float* __restrict__ Whh0,
    const float* __restrict__ bih0, const float* __restrict__ bhh0,
    const float* __restrict__ Wih1, const float* __restrict__ Whh1,
    const float* __restrict__ bih1, const float* __restrict__ bhh1,
    const float* __restrict__ Wfc,  const float* __restrict__ bfc,
    float* __restrict__ out,
    uint* __restrict__ h0g, uint* __restrict__ h1g, uint* __restrict__ flags)
{
  __shared__ __align__(16) ushort hBh[2][NB][KP];
  __shared__ __align__(16) ushort hBl[2][NB][KP];
  __shared__ float D[117][17];
  __shared__ float Wi0[39][8];
  __shared__ float bi0[39], bh0[39], bi1[39], bh1[39], bfs[4];
  __shared__ float xc[NB][8];

  const int tid  = threadIdx.x;
  const int wave = tid >> 6;
  const int lane = tid & 63;
  const int m15  = lane & 15;
  const int q    = lane >> 4;

  const int g  = blockIdx.x & 7;    // batch-group
  const int s  = blockIdx.x >> 3;   // hidden-slice
  const int b0 = g * NB;
  const int j0 = s * HS;
  const int hs = (HH - j0 < HS) ? (HH - j0) : HS;   // 13 (s<15) or 5 (s==15)
  const int th   = 3 * hs;
  const int h0r  = 6 * hs;                          // rows dotted with h0
  const int T0   = (h0r + 15) >> 4;                 // 5 or 2  (h0 tiles)
  const int NT   = T0 + ((th + 15) >> 4);           // 8 or 3  (total tiles)
  const bool isOut = (s == 15);

  // ---- one-time: weight A-fragments into registers (hi/lo bf16) ----
  short8 Ah[2][7], Al[2][7];
  #pragma unroll
  for (int mt = 0; mt < 2; ++mt) {
    const int T = wave * 2 + mt;
    const bool fc  = isOut && (wave == 2) && (mt == 0);
    const bool val = fc || (T < NT);
    #pragma unroll
    for (int kt = 0; kt < 7; ++kt) {
      short8 vh = {0,0,0,0,0,0,0,0}, vl = {0,0,0,0,0,0,0,0};
      #pragma unroll
      for (int j = 0; j < 8; ++j) {
        const int k = kt * 32 + q * 8 + j;
        float w = 0.0f;
        if (val && k < HH) {
          if (fc) {
            if (m15 < 4) w = Wfc[m15 * HH + k];
          } else {
            const int p = T * 16 + m15;
            int r = -1;
            if (p < h0r) r = p;
            else if (p >= T0 * 16 && (p - T0 * 16) < th) r = h0r + (p - T0 * 16);
            if (r >= 0) {
              const int m  = r / th, rr = r - m * th;
              const int qq = rr / hs, jj = rr - qq * hs;
              const float* src = (m == 0) ? Whh0 : ((m == 1) ? Wih1 : Whh1);
              w = src[(qq * HH + j0 + jj) * HH + k];
            }
          }
        }
        const ushort uh = f2bfu(w);
        const ushort ul = f2bfu(w - bfu2f(uh));
        vh[j] = (short)uh; vl[j] = (short)ul;
      }
      Ah[mt][kt] = vh; Al[mt][kt] = vl;
    }
  }

  // ---- one-time: small LDS tables ----
  for (int u = tid; u < th * 8; u += 256) {
    int rr = u >> 3, c = u & 7;
    int qq = rr / hs, jj = rr - qq * hs;
    Wi0[rr][c] = Wih0[(qq * HH + j0 + jj) * 8 + c];
  }
  for (int u = tid; u < th; u += 256) {
    int qq = u / hs, jj = u - qq * hs;
    int grow = qq * HH + j0 + jj;
    bi0[u] = bih0[grow]; bh0[u] = bhh0[grow];
    bi1[u] = bih1[grow]; bh1[u] = bhh1[grow];
  }
  if (tid < 4) bfs[tid] = bfc[tid];
  for (int u = tid; u < 2 * NB * KP / 2; u += 256) ((uint*)hBh)[u] = 0;  // zero pads
  for (int u = tid; u < 2 * NB * KP / 2; u += 256) ((uint*)hBl)[u] = 0;
  __syncthreads();

  // ---- staging map precompute: u = tid + 256*i over [0,6400) ----
  // Coalesced (R3/R6 mapping): st = u/3200, b = rem/200, k = rem%200.
  int boff[25], lofs[25]; uint stm = 0;
  #pragma unroll
  for (int i = 0; i < 25; ++i) {
    const int u   = tid + i * 256;
    const int st  = (u >= 3200) ? 1 : 0;
    const int rem = u - st * 3200;
    const int b   = rem / 200;
    const int k   = rem - b * 200;
    boff[i] = (b0 + b) * HH + k;
    lofs[i] = (st * NB + b) * KP + k;
    if (st) stm |= (1u << i);
  }
  ushort* const hBhF = &hBh[0][0][0];
  ushort* const hBlF = &hBl[0][0][0];

  uint* const flg = flags + g * 32;   // 16 flags in one 64B line; 128B group stride
  const int cj = tid >> 4, cb = tid & 15;   // gate-combine indices

  for (int t = 0; t <= TT + 1; ++t) {
    // ---- x(t) staging first (flag-independent; overlaps the poll) ----
    if (tid < 128 && t < TT) {
      int b = tid >> 3, c = tid & 7;
      float xv;
      if (c < 4) xv = (t == 0) ? 1.0f : x[((b0 + b) * TT + (t - 1)) * 8 + c];
      else       xv = x[(b0 + b) * TT * 8 + c];
      xc[b][c] = xv;
    }

    // ---- wait: all 16 producer flags >= t (no RMW, one 64B line) ----
    if (wave == 0) {
      const uint tgt = (uint)t;
      for (;;) {
        uint f = tgt;
        if (lane < 16) f = llc_load_u32(flg + lane);
        if (__all((int)(f >= tgt))) break;
        __builtin_amdgcn_s_sleep(1);
      }
    }
    __syncthreads();

    // ---- stage h0(t-1), h1(t-2): packed bf16 hi/lo from LLC -> LDS planes ----
    const uint* h0src = h0g + ((t + 1) & 1) * (128 * HH);
    const uint* h1src = h1g + (t & 1) * (128 * HH);
    uint v[25];
    #pragma unroll
    for (int i = 0; i < 25; ++i)
      v[i] = llc_load_u32((((stm >> i) & 1) ? h1src : h0src) + boff[i]);
    #pragma unroll
    for (int i = 0; i < 25; ++i) {
      hBhF[lofs[i]] = (ushort)(v[i] & 0xffffu);
      hBlF[lofs[i]] = (ushort)(v[i] >> 16);
    }
    __syncthreads();   // bar1

    // ---- MFMA: D[rows x 16 batch] = W * h, bf16x3; B shared per st ----
    {
      const int  Ta = 2 * wave, Tb = Ta + 1;
      const bool fa = isOut && (wave == 2);        // FC tile = wave2/mt0
      const bool va = (Ta < NT) || fa;
      const bool vb = (Tb < NT);
      const int  sa = fa ? 1 : ((Ta < T0) ? 0 : 1);
      const int  sb = (Tb < T0) ? 0 : 1;
      f32x4 acc0 = {0.f,0.f,0.f,0.f}, acc1 = {0.f,0.f,0.f,0.f};
      #pragma unroll
      for (int st = 0; st < 2; ++st) {
        const bool nA = va && (sa == st), nB = vb && (sb == st);
        if (!(nA || nB)) continue;
        const ushort* bh = &hBh[st][m15][0];
        const ushort* bl = &hBl[st][m15][0];
        #pragma unroll
        for (int kt = 0; kt < 7; ++kt) {
          const short8 Bh = *(const short8*)(bh + kt * 32 + q * 8);
          const short8 Bl = *(const short8*)(bl + kt * 32 + q * 8);
          if (nA) {
            acc0 = __builtin_amdgcn_mfma_f32_16x16x32_bf16(Ah[0][kt], Bh, acc0, 0, 0, 0);
            acc0 = __builtin_amdgcn_mfma_f32_16x16x32_bf16(Ah[0][kt], Bl, acc0, 0, 0, 0);
            acc0 = __builtin_amdgcn_mfma_f32_16x16x32_bf16(Al[0][kt], Bh, acc0, 0, 0, 0);
          }
          if (nB) {
            acc1 = __builtin_amdgcn_mfma_f32_16x16x32_bf16(Ah[1][kt], Bh, acc1, 0, 0, 0);
            acc1 = __builtin_amdgcn_mfma_f32_16x16x32_bf16(Ah[1][kt], Bl, acc1, 0, 0, 0);
            acc1 = __builtin_amdgcn_mfma_f32_16x16x32_bf16(Al[1][kt], Bh, acc1, 0, 0, 0);
          }
        }
      }
      if (fa) {                              // FC head: out(t-2)
        if (t >= 2) {
          #pragma unroll
          for (int i = 0; i < 4; ++i) {
            const int p = q * 4 + i;
            if (p < 4)
              out[((b0 + m15) * TT + (t - 2)) * 4 + p] = tanh_fast(acc0[i] + bfs[p]);
          }
        }
      } else if (va) {
        #pragma unroll
        for (int i = 0; i < 4; ++i) {
          const int p = Ta * 16 + q * 4 + i;
          int r = -1;
          if (p < h0r) r = p;
          else if (p >= T0 * 16 && (p - T0 * 16) < th) r = h0r + (p - T0 * 16);
          if (r >= 0) D[r][m15] = acc0[i];
        }
      }
      if (vb) {
        #pragma unroll
        for (int i = 0; i < 4; ++i) {
          const int p = Tb * 16 + q * 4 + i;
          int r = -1;
          if (p < h0r) r = p;
          else if (p >= T0 * 16 && (p - T0 * 16) < th) r = h0r + (p - T0 * 16);
          if (r >= 0) D[r][m15] = acc1[i];
        }
      }
    }
    __syncthreads();   // bar2

    // ---- gate combine + state update (packed stores to LLC) ----
    if (cj < hs) {
      const float hv0 = bfu2f(hBh[0][cb][j0 + cj]) + bfu2f(hBl[0][cb][j0 + cj]);
      const float hv1 = bfu2f(hBh[1][cb][j0 + cj]) + bfu2f(hBl[1][cb][j0 + cj]);
      if (t < TT) {                 // h0(t)
        float ir = bi0[cj], iz = bi0[hs + cj], in_ = bi0[2 * hs + cj];
        #pragma unroll
        for (int c = 0; c < 8; ++c) {
          const float xv = xc[cb][c];
          ir  += Wi0[cj][c] * xv;
          iz  += Wi0[hs + cj][c] * xv;
          in_ += Wi0[2 * hs + cj][c] * xv;
        }
        const float hr = D[cj][cb] + bh0[cj];
        const float hz = D[hs + cj][cb] + bh0[hs + cj];
        const float hn = D[2 * hs + cj][cb] + bh0[2 * hs + cj];
        const float r = sigm(ir + hr), z = sigm(iz + hz);
        const float n = tanh_fast(in_ + r * hn);
        llc_store_u32(&h0g[(t & 1) * (128 * HH) + (b0 + cb) * HH + j0 + cj],
                      packf((1.0f - z) * n + z * hv0));
      }
      if (t >= 1 && t <= TT) {      // h1(t-1)
        const float ir  = D[3 * hs + cj][cb] + bi1[cj];
        const float iz  = D[4 * hs + cj][cb] + bi1[hs + cj];
        const float in_ = D[5 * hs + cj][cb] + bi1[2 * hs + cj];
        const float hr  = D[6 * hs + cj][cb] + bh1[cj];
        const float hz  = D[7 * hs + cj][cb] + bh1[hs + cj];
        const float hn  = D[8 * hs + cj][cb] + bh1[2 * hs + cj];
        const float r = sigm(ir + hr), z = sigm(iz + hz);
        const float n = tanh_fast(in_ + r * hn);
        llc_store_u32(&h1g[((t + 1) & 1) * (128 * HH) + (b0 + cb) * HH + j0 + cj],
                      packf((1.0f - z) * n + z * hv1));
      }
    }

    // ---- signal: drain stores (syncthreads waits vmcnt(0)), then flag=t+1 ----
    __syncthreads();
    if (tid == 0) llc_store_u32(flg + s, (uint)(t + 1));
  }
}

extern "C" void kernel_launch(void* const* d_in, const int* in_sizes, int n_in,
                              void* d_out, int out_size, void* d_ws, size_t ws_size,
                              hipStream_t stream) {
  uint* ws = (uint*)d_ws;
  // ws (u32): h0g[2][128][200] @0, h1g[2][128][200] @51200,
  // flags (8 groups x 32 u32 stride, 16 used each) @102400. memset -> flags=0.
  hipMemsetAsync(d_ws, 0, (size_t)(102400 + 512) * sizeof(uint), stream);
  gru2_mfma<<<128, 256, 0, stream>>>(
      (const float*)d_in[0],
      (const float*)d_in[1], (const float*)d_in[2],
      (const float*)d_in[3], (const float*)d_in[4],
      (const float*)d_in[5], (const float*)d_in[6],
      (const float*)d_in[7], (const float*)d_in[8],
      (const float*)d_in[9], (const float*)d_in[10],
      (float*)d_out, ws, ws + 51200, ws + 102400);
}